// Round 6
// baseline (187.685 us; speedup 1.0000x reference)
//
#include <hip/hip_runtime.h>
#include <cstddef>
#include <cstdint>

// ---------------- problem constants ----------------
#define cB   512
#define cV   5023
#define cS   100
#define cE   50
#define cJ   5
#define cLD  17
#define cLF  68

#define cV3    15069       // V*3
#define cNPAD  15072       // 157*96 padded N (BTn rows; 314*48 = 15072 too)

#define OUT_V  ((size_t)cB * cV * 3)
#define OUT_L  ((size_t)cB * cLF * 3)

// ws layout (dword offsets)
#define WS_BTN    ((size_t)0)                      // 15072*96 dwords (bf16 x2)
#define WS_ATM    (WS_BTN + (size_t)cNPAD * 96)    // 512*96 dwords
#define WS_JS2    (WS_ATM + 49152)                 // 2432 floats
#define WS_AREL   (WS_JS2 + 2432)                  // 512*60 floats
#define WS_YROT   (WS_AREL + 30720)                // 512 ints
#define WS_JSPART (WS_YROT + 512)                  // 236*2272 floats (was 314)

typedef __attribute__((ext_vector_type(8))) short short8;
typedef __attribute__((ext_vector_type(4))) float f32x4;

// fp32 -> bf16 round-to-nearest-even
__device__ __forceinline__ unsigned short f2bf(float x) {
  unsigned int u = __float_as_uint(x);
  u = (u + 0x7fffu + ((u >> 16) & 1u)) >> 16;
  return (unsigned short)u;
}

// ---------------- rodrigues (matches jax reference in fp32) ----------------
__device__ __forceinline__ void rodrigues9(float rx, float ry, float rz, float* R) {
  float a0 = rx + 1e-8f, a1 = ry + 1e-8f, a2 = rz + 1e-8f;
  float angle = sqrtf(a0 * a0 + a1 * a1 + a2 * a2);
  float inv = 1.0f / angle;
  float x = rx * inv, y = ry * inv, z = rz * inv;
  float s = sinf(angle), c = cosf(angle);
  float t = 1.0f - c;
  float xy = x * y, xz = x * z, yz = y * z;
  R[0] = 1.0f - t * (y * y + z * z);
  R[1] = -s * z + t * xy;
  R[2] =  s * y + t * xz;
  R[3] =  s * z + t * xy;
  R[4] = 1.0f - t * (x * x + z * z);
  R[5] = -s * x + t * yz;
  R[6] = -s * y + t * xz;
  R[7] =  s * x + t * yz;
  R[8] = 1.0f - t * (x * x + y * y);
}

// ---------------- k_aux UNIFIED: 236 blocks; each stages 64 BTn rows of sd ONCE
// and produces BOTH the bf16 BTn rows AND the JS partials for those rows.
// (r5 lesson: old split read sd twice, 9 MB extra; this reads it once.)
__global__ __launch_bounds__(512) void k_aux(
    const float* __restrict__ sd, const float* __restrict__ pd,
    const float* __restrict__ jreg, const float* __restrict__ vt,
    unsigned int* __restrict__ btn_u, float* __restrict__ JSpart) {
  __shared__ __align__(16) unsigned char sm[44544];
  float* sdt = (float*)sm;                          // 64 x 152 f32 @0      (38,912 B)
  unsigned short* pdt = (unsigned short*)(sm + 38912); // 64 x 38 bf16      ( 4,864 B)
  float* vtc = (float*)(sm + 43776);                // 64 f32               (   256 B)
  float* jt  = (float*)(sm + 44032);                // 5 x 22 f32           (   440 B)
  const int t = threadIdx.x;
  const int bid = blockIdx.x;                       // 0..235
  const int n0 = bid * 64;
  const int v0 = n0 / 3;

  // sd rows (linear, coalesced; rows >= cV3 zeroed)
  for (int idx = t; idx < 9600; idx += 512) {
    size_t g = (size_t)n0 * 150 + idx;
    float v = (g < (size_t)cV3 * 150) ? sd[g] : 0.f;
    int row = idx / 150, col = idx - row * 150;
    sdt[row * 152 + col] = v;
  }
  // pd columns (coalesced over n)
  for (int e = t; e < 2304; e += 512) {
    int kk = e >> 6, ln = e & 63;
    int n = n0 + ln;
    pdt[ln * 38 + kk] = f2bf((n < cV3) ? pd[(size_t)kk * cV3 + n] : 0.f);
  }
  // v_template values for these rows (JS l=150 term)
  if (t < 64) {
    int n = n0 + t;
    vtc[t] = (n < cV3) ? vt[n] : 0.f;
  }
  // jreg slice: 5 joints x 22 vertices covered by this block
  if (t >= 64 && t < 174) {
    int e = t - 64;
    int j = e / 22, vi = e - j * 22;
    int v = v0 + vi;
    jt[j * 22 + vi] = (v < cV) ? jreg[j * cV + v] : 0.f;
  }
  __syncthreads();

  // JS partials: thread (c,l); sum over the ~22 vertices whose row 3v+c is here
  if (t < 453) {
    int c = t / 151, l = t - c * 151;
    const int base = 3 * v0 + c - n0;               // row of vertex v0, component c
    float acc[5] = {0.f, 0.f, 0.f, 0.f, 0.f};
#pragma unroll
    for (int vi = 0; vi < 22; ++vi) {
      int r = base + 3 * vi;
      if (r >= 0 && r < 64) {
        float x = (l < 150) ? sdt[r * 152 + l] : vtc[r];
#pragma unroll
        for (int j = 0; j < 5; ++j)
          acc[j] = fmaf(jt[j * 22 + vi], x, acc[j]);
      }
    }
#pragma unroll
    for (int j = 0; j < 5; ++j)
      JSpart[(size_t)bid * 2272 + (j * 3 + c) * 151 + l] = acc[j];
  }

  // emit BTn rows (96 dwords each), coalesced
  for (int e = t; e < 6144; e += 512) {
    int row = e / 96, d = e - row * 96;
    int n = n0 + row;
    if (n < cNPAD) {
      unsigned int wv;
      if (d < 75) {
        wv = (unsigned int)f2bf(sdt[row * 152 + 2 * d]) |
             ((unsigned int)f2bf(sdt[row * 152 + 2 * d + 1]) << 16);
      } else if (d < 93) {
        int p = (d - 75) * 2;
        wv = (unsigned int)pdt[row * 38 + p] |
             ((unsigned int)pdt[row * 38 + p + 1] << 16);
      } else {
        wv = 0u;
      }
      btn_u[(size_t)n * 96 + d] = wv;
    }
  }
}

// ---------------- k_jsred: 236 partials -> JS2[l][16]; 8 threads per element ----------------
__global__ __launch_bounds__(256) void k_jsred(const float* __restrict__ JSpart,
                                               float* __restrict__ JS2) {
  __shared__ float red[256];
  const int t = threadIdx.x;
  const int e = blockIdx.x * 32 + (t & 31);
  const int pg = t >> 5;
  float s = 0.f;
  if (e < 2265) {
#pragma unroll 8
    for (int p = pg; p < 236; p += 8)
      s += JSpart[(size_t)p * 2272 + e];
  }
  red[t] = s;
  __syncthreads();
  if (t < 128) red[t] += red[t + 128];
  __syncthreads();
  if (t < 64) red[t] += red[t + 64];
  __syncthreads();
  if (t < 32) {
    float v = red[t] + red[t + 32];
    if (e < 2265) {
      int jc = e / 151, l = e - jc * 151;
      JS2[l * 16 + jc] = v;
    }
  }
}

// ---------------- k_batch: joints, rot mats, chain, A_rel, y_rot + ATm bf16 rows ----------
__global__ __launch_bounds__(256) void k_batch(
    const float* __restrict__ shp, const float* __restrict__ expr,
    const float* __restrict__ pose, const float* __restrict__ eyep,
    const float* __restrict__ JS2g, float* __restrict__ Arel,
    int* __restrict__ yrot, unsigned int* __restrict__ atm_u) {
  __shared__ float js2[151 * 16];
  __shared__ float sb[32 * 153];
  __shared__ float pfs[32 * 36];
  const int t = threadIdx.x;
  const int b0 = blockIdx.x * 32;
  for (int i = t; i < 151 * 16; i += 256) js2[i] = JS2g[i];
  for (int e = t; e < 3200; e += 256) {
    int bl = e / 100, l = e - bl * 100;
    sb[bl * 153 + l] = shp[(size_t)(b0 + bl) * 100 + l];
  }
  for (int e = t; e < 1600; e += 256) {
    int bl = e / 50, l = e - bl * 50;
    sb[bl * 153 + 100 + l] = expr[(size_t)(b0 + bl) * 50 + l];
  }
  __syncthreads();

  if (t < 32) {
    int b = b0 + t;
    float jnt[5][3];
    {
      const f32x4* J4 = (const f32x4*)(js2 + 150 * 16);
      f32x4 A = J4[0], Bq = J4[1], Cq = J4[2], Dq = J4[3];
      jnt[0][0] = A.x;  jnt[0][1] = A.y;  jnt[0][2] = A.z;
      jnt[1][0] = A.w;  jnt[1][1] = Bq.x; jnt[1][2] = Bq.y;
      jnt[2][0] = Bq.z; jnt[2][1] = Bq.w; jnt[2][2] = Cq.x;
      jnt[3][0] = Cq.y; jnt[3][1] = Cq.z; jnt[3][2] = Cq.w;
      jnt[4][0] = Dq.x; jnt[4][1] = Dq.y; jnt[4][2] = Dq.z;
    }
    for (int l = 0; l < 150; ++l) {
      const f32x4* J4 = (const f32x4*)(js2 + l * 16);
      f32x4 A = J4[0], Bq = J4[1], Cq = J4[2], Dq = J4[3];
      float beta = sb[t * 153 + l];
      jnt[0][0] = fmaf(beta, A.x,  jnt[0][0]);
      jnt[0][1] = fmaf(beta, A.y,  jnt[0][1]);
      jnt[0][2] = fmaf(beta, A.z,  jnt[0][2]);
      jnt[1][0] = fmaf(beta, A.w,  jnt[1][0]);
      jnt[1][1] = fmaf(beta, Bq.x, jnt[1][1]);
      jnt[1][2] = fmaf(beta, Bq.y, jnt[1][2]);
      jnt[2][0] = fmaf(beta, Bq.z, jnt[2][0]);
      jnt[2][1] = fmaf(beta, Bq.w, jnt[2][1]);
      jnt[2][2] = fmaf(beta, Cq.x, jnt[2][2]);
      jnt[3][0] = fmaf(beta, Cq.y, jnt[3][0]);
      jnt[3][1] = fmaf(beta, Cq.z, jnt[3][1]);
      jnt[3][2] = fmaf(beta, Cq.w, jnt[3][2]);
      jnt[4][0] = fmaf(beta, Dq.x, jnt[4][0]);
      jnt[4][1] = fmaf(beta, Dq.y, jnt[4][1]);
      jnt[4][2] = fmaf(beta, Dq.z, jnt[4][2]);
    }
    float fp[5][3];
    fp[0][0] = pose[b * 6 + 0]; fp[0][1] = pose[b * 6 + 1]; fp[0][2] = pose[b * 6 + 2];
    fp[1][0] = 0.f; fp[1][1] = 0.f; fp[1][2] = 0.f;
    fp[2][0] = pose[b * 6 + 3]; fp[2][1] = pose[b * 6 + 4]; fp[2][2] = pose[b * 6 + 5];
    fp[3][0] = eyep[b * 6 + 0]; fp[3][1] = eyep[b * 6 + 1]; fp[3][2] = eyep[b * 6 + 2];
    fp[4][0] = eyep[b * 6 + 3]; fp[4][1] = eyep[b * 6 + 4]; fp[4][2] = eyep[b * 6 + 5];
    float R[5][9];
#pragma unroll
    for (int j = 0; j < 5; ++j) rodrigues9(fp[j][0], fp[j][1], fp[j][2], R[j]);
#pragma unroll
    for (int j = 1; j < 5; ++j)
#pragma unroll
      for (int r = 0; r < 9; ++r) {
        float id = (r == 0 || r == 4 || r == 8) ? 1.f : 0.f;
        pfs[t * 36 + (j - 1) * 9 + r] = R[j][r] - id;
      }
    float rel[5][3];
#pragma unroll
    for (int c = 0; c < 3; ++c) {
      rel[0][c] = jnt[0][c];
      rel[1][c] = jnt[1][c] - jnt[0][c];
      rel[2][c] = jnt[2][c] - jnt[1][c];
      rel[3][c] = jnt[3][c] - jnt[1][c];
      rel[4][c] = jnt[4][c] - jnt[1][c];
    }
    float GR[5][9], Gt[5][3];
#pragma unroll
    for (int r = 0; r < 9; ++r) GR[0][r] = R[0][r];
#pragma unroll
    for (int c = 0; c < 3; ++c) Gt[0][c] = rel[0][c];
    const int par[5] = {0, 0, 1, 1, 1};
#pragma unroll
    for (int j = 1; j < 5; ++j) {
      int p = par[j];
#pragma unroll
      for (int r = 0; r < 3; ++r) {
#pragma unroll
        for (int cc = 0; cc < 3; ++cc)
          GR[j][r * 3 + cc] = GR[p][r * 3 + 0] * R[j][0 + cc] +
                              GR[p][r * 3 + 1] * R[j][3 + cc] +
                              GR[p][r * 3 + 2] * R[j][6 + cc];
        Gt[j][r] = Gt[p][r] + GR[p][r * 3 + 0] * rel[j][0] +
                              GR[p][r * 3 + 1] * rel[j][1] +
                              GR[p][r * 3 + 2] * rel[j][2];
      }
    }
#pragma unroll
    for (int j = 0; j < 5; ++j)
#pragma unroll
      for (int r = 0; r < 3; ++r) {
        float tj = Gt[j][r] - (GR[j][r * 3 + 0] * jnt[j][0] +
                               GR[j][r * 3 + 1] * jnt[j][1] +
                               GR[j][r * 3 + 2] * jnt[j][2]);
        Arel[b * 60 + j * 12 + r * 4 + 0] = GR[j][r * 3 + 0];
        Arel[b * 60 + j * 12 + r * 4 + 1] = GR[j][r * 3 + 1];
        Arel[b * 60 + j * 12 + r * 4 + 2] = GR[j][r * 3 + 2];
        Arel[b * 60 + j * 12 + r * 4 + 3] = tj;
      }
    float Ra[9], Rb[9];
    rodrigues9(fp[1][0], fp[1][1], fp[1][2], Ra);
    rodrigues9(fp[0][0], fp[0][1], fp[0][2], Rb);
    float r00 = Rb[0] * Ra[0] + Rb[1] * Ra[3] + Rb[2] * Ra[6];
    float r10 = Rb[3] * Ra[0] + Rb[4] * Ra[3] + Rb[5] * Ra[6];
    float r20 = Rb[6] * Ra[0] + Rb[7] * Ra[3] + Rb[8] * Ra[6];
    float sy = sqrtf(r00 * r00 + r10 * r10);
    float ydeg = atan2f(-r20, sy) * 57.29577951308232f;
    int y = (int)rintf(fminf(ydeg, 39.0f));
    if (y < 0) y = (y < -39) ? 78 : (39 - y);
    yrot[b] = y;
  }
  __syncthreads();

#pragma unroll
  for (int it = 0; it < 12; ++it) {
    int e = t + it * 256;
    int bl = e / 96, d = e - bl * 96;
    unsigned int wv;
    if (d < 75) {
      wv = (unsigned int)f2bf(sb[bl * 153 + 2 * d]) |
           ((unsigned int)f2bf(sb[bl * 153 + 2 * d + 1]) << 16);
    } else if (d < 93) {
      wv = (unsigned int)f2bf(pfs[bl * 36 + (d - 75) * 2]) |
           ((unsigned int)f2bf(pfs[bl * 36 + (d - 75) * 2 + 1]) << 16);
    } else {
      wv = 0u;
    }
    atm_u[(size_t)(b0 + bl) * 96 + d] = wv;
  }
}

// ---------------- k_main v6: 2512 SINGLE-WAVE blocks (64 thr), tile = 64 b x 16 v.
// Theory: 4-wave barrier-coupled blocks at <=3/CU starved the latency-hiding
// (r2: occupancy 8% => ~0.6 blocks/CU avg). 1-wave blocks: zero barriers, 12
// waves/CU, 82% of device resident+independent. B redundancy unchanged (8x);
// A redundancy 314x but A = 196 KB, L2-resident (~1.7 us aggregate).
// Tripwires: FETCH > 15 MB = A/B leaked past L2/L3; WRITE ~31.6 MB.
__global__ __launch_bounds__(64) void k_main(
    const unsigned short* __restrict__ BTn, const unsigned short* __restrict__ ATm,
    const float* __restrict__ Arel, const float* __restrict__ vtempl,
    const float* __restrict__ lbw, float* __restrict__ out) {
  __shared__ float Pf[48 * 66];          // 12,672 B: [n_loc][m] transpose

  const int bid = blockIdx.x;            // 2512 = 314 nb * 8 mb (nb-adjacent)
  const int nb = bid >> 3, mb = bid & 7;
  const int L = threadIdx.x;             // 0..63
  const int lr = L & 15, lq = L >> 4;

  const unsigned short* abase = ATm + ((size_t)mb * 64 + lr) * 192 + lq * 8;
  const unsigned short* bbase = BTn + ((size_t)nb * 48 + lr) * 192 + lq * 8;

  f32x4 acc[4][3];
#pragma unroll
  for (int mt = 0; mt < 4; ++mt)
#pragma unroll
    for (int nt = 0; nt < 3; ++nt) acc[mt][nt] = (f32x4){0.f, 0.f, 0.f, 0.f};

  // depth-2 ring: 4 A-frags (m-tiles) + 3 B-frags (n-tiles) per k-step
  short8 Ar[2][4], Br[2][3];
#pragma unroll
  for (int mt = 0; mt < 4; ++mt) Ar[0][mt] = *(const short8*)(abase + mt * 16 * 192);
#pragma unroll
  for (int nt = 0; nt < 3; ++nt) Br[0][nt] = *(const short8*)(bbase + nt * 16 * 192);

#pragma unroll
  for (int ks = 0; ks < 6; ++ks) {
    const int cur = ks & 1, nxt = cur ^ 1;   // static after unroll
    if (ks < 5) {
      const int ko = (ks + 1) * 32;
#pragma unroll
      for (int mt = 0; mt < 4; ++mt)
        Ar[nxt][mt] = *(const short8*)(abase + mt * 16 * 192 + ko);
#pragma unroll
      for (int nt = 0; nt < 3; ++nt)
        Br[nxt][nt] = *(const short8*)(bbase + nt * 16 * 192 + ko);
    }
#pragma unroll
    for (int nt = 0; nt < 3; ++nt)
#pragma unroll
      for (int mt = 0; mt < 4; ++mt)
        acc[mt][nt] = __builtin_amdgcn_mfma_f32_16x16x32_bf16(
            Ar[cur][mt], Br[cur][nt], acc[mt][nt], 0, 0, 0);
  }

  // acc -> Pf[n_loc][m]  (C layout: col(lane&15)->n, row((lane>>4)*4+reg)->m)
#pragma unroll
  for (int mt = 0; mt < 4; ++mt)
#pragma unroll
    for (int nt = 0; nt < 3; ++nt) {
      int n_loc = nt * 16 + lr;
      int m = mt * 16 + lq * 4;
      *(f32x4*)(Pf + n_loc * 66 + m) = acc[mt][nt];
    }

  // lane L owns batch b = mb*64 + L for the whole epilogue
  const int b = mb * 64 + L;
  const float* qb = Arel + (size_t)b * 60;
  f32x4 ar[15];
#pragma unroll
  for (int r = 0; r < 15; ++r) ar[r] = *(const f32x4*)(qb + 4 * r);

  // single wave: ds_write -> ds_read ordering handled by compiler waitcnt; no barrier
  const int vg0 = nb * 16;
  float* ob = out + ((size_t)b * cV + vg0) * 3;
#pragma unroll
  for (int vl = 0; vl < 16; ++vl) {
    const int v = vg0 + vl;
    if (v < cV) {                         // uniform across lanes
      float px = Pf[(vl * 3 + 0) * 66 + L] + vtempl[v * 3 + 0];
      float py = Pf[(vl * 3 + 1) * 66 + L] + vtempl[v * 3 + 1];
      float pz = Pf[(vl * 3 + 2) * 66 + L] + vtempl[v * 3 + 2];
      float o0 = 0.f, o1 = 0.f, o2 = 0.f;
#pragma unroll
      for (int j = 0; j < 5; ++j) {
        f32x4 q0 = ar[3 * j + 0], q1 = ar[3 * j + 1], q2 = ar[3 * j + 2];
        float s0 = q0.x * px + q0.y * py + q0.z * pz + q0.w;
        float s1 = q1.x * px + q1.y * py + q1.z * pz + q1.w;
        float s2 = q2.x * px + q2.y * py + q2.z * pz + q2.w;
        float wj = lbw[v * 5 + j];        // uniform -> scalar broadcast
        o0 = fmaf(wj, s0, o0);
        o1 = fmaf(wj, s1, o1);
        o2 = fmaf(wj, s2, o2);
      }
      ob[vl * 3 + 0] = o0;
      ob[vl * 3 + 1] = o1;
      ob[vl * 3 + 2] = o2;
    }
  }
}

// ---------------- k_lmk: barycentric landmark gather, component-parallel:
// 1 thread per (b, l, which, c) -> 3x waves, 3 gathers/thread (latency hiding) ----
__global__ __launch_bounds__(512) void k_lmk(
    const float* __restrict__ verts, const int* __restrict__ faces,
    const int* __restrict__ lmkf, const float* __restrict__ lmkb,
    const int* __restrict__ dynf, const float* __restrict__ dynb,
    const int* __restrict__ fullf, const float* __restrict__ fullb,
    const int* __restrict__ yrot, float* __restrict__ out) {
  int id = blockIdx.x * 512 + threadIdx.x;
  if (id >= cB * cLF * 6) return;
  int c = id % 3;
  int q = id / 3;
  int sel = q & 1;
  int r = q >> 1;
  int b = r / cLF, l = r - b * cLF;
  const float* vb = verts + (size_t)b * cV * 3;
  int f; float w0, w1, w2; size_t o;
  if (sel == 0) {
    if (l < cLD) {
      int yb = yrot[b];
      f = dynf[yb * cLD + l];
      const float* bp = dynb + ((size_t)yb * cLD + l) * 3;
      w0 = bp[0]; w1 = bp[1]; w2 = bp[2];
    } else {
      f = lmkf[l - cLD];
      const float* bp = lmkb + (size_t)(l - cLD) * 3;
      w0 = bp[0]; w1 = bp[1]; w2 = bp[2];
    }
    o = OUT_V + ((size_t)b * cLF + l) * 3;
  } else {
    f = fullf[l];
    const float* bp = fullb + (size_t)l * 3;
    w0 = bp[0]; w1 = bp[1]; w2 = bp[2];
    o = OUT_V + OUT_L + ((size_t)b * cLF + l) * 3;
  }
  int i0 = faces[f * 3 + 0] * 3, i1 = faces[f * 3 + 1] * 3, i2 = faces[f * 3 + 2] * 3;
  out[o + c] = w0 * vb[i0 + c] + w1 * vb[i1 + c] + w2 * vb[i2 + c];
}

// ---------------- launch ----------------
extern "C" void kernel_launch(void* const* d_in, const int* in_sizes, int n_in,
                              void* d_out, int out_size, void* d_ws, size_t ws_size,
                              hipStream_t stream) {
  (void)in_sizes; (void)n_in; (void)out_size; (void)ws_size;
  const float* shp  = (const float*)d_in[0];
  const float* expr = (const float*)d_in[1];
  const float* pose = (const float*)d_in[2];
  const float* eyep = (const float*)d_in[3];
  const float* vt   = (const float*)d_in[4];
  const float* sd   = (const float*)d_in[5];
  const float* pd   = (const float*)d_in[6];
  const float* jreg = (const float*)d_in[7];
  const float* lbw  = (const float*)d_in[8];
  const int*   fcs  = (const int*)d_in[9];
  const int*   lmkf = (const int*)d_in[10];
  const float* lmkb = (const float*)d_in[11];
  const int*   dynf = (const int*)d_in[12];
  const float* dynb = (const float*)d_in[13];
  const int*   fullf= (const int*)d_in[14];
  const float* fullb= (const float*)d_in[15];
  float* out = (float*)d_out;
  float* ws  = (float*)d_ws;

  unsigned int*   btn  = (unsigned int*)(ws + WS_BTN);
  unsigned short* ATm  = (unsigned short*)(ws + WS_ATM);
  float* JS2    = ws + WS_JS2;
  float* Arel   = ws + WS_AREL;
  int*   yrot   = (int*)(ws + WS_YROT);
  float* JSpart = ws + WS_JSPART;

  k_aux<<<236, 512, 0, stream>>>(sd, pd, jreg, vt, btn, JSpart);
  k_jsred<<<71, 256, 0, stream>>>(JSpart, JS2);
  k_batch<<<16, 256, 0, stream>>>(shp, expr, pose, eyep, JS2, Arel, yrot,
                                  (unsigned int*)ATm);
  k_main<<<2512, 64, 0, stream>>>((unsigned short*)btn, ATm, Arel, vt, lbw, out);
  k_lmk<<<408, 512, 0, stream>>>(out, fcs, lmkf, lmkb, dynf, dynb, fullf, fullb, yrot, out);
}

// Round 7
// 183.531 us; speedup vs baseline: 1.0226x; 1.0226x over previous
//
#include <hip/hip_runtime.h>
#include <cstddef>
#include <cstdint>

// ---------------- problem constants ----------------
#define cB   512
#define cV   5023
#define cS   100
#define cE   50
#define cJ   5
#define cLD  17
#define cLF  68

#define cV3    15069       // V*3
#define cNPAD  15072       // 157*96 padded N (BTn rows; 314*48 = 15072 too)

#define OUT_V  ((size_t)cB * cV * 3)
#define OUT_L  ((size_t)cB * cLF * 3)

// ws layout (dword offsets)
#define WS_BTN    ((size_t)0)                      // 15072*96 dwords (bf16 x2)
#define WS_ATM    (WS_BTN + (size_t)cNPAD * 96)    // 512*96 dwords
#define WS_JS2    (WS_ATM + 49152)                 // 2432 floats
#define WS_AREL   (WS_JS2 + 2432)                  // 512*60 floats
#define WS_YROT   (WS_AREL + 30720)                // 512 ints
#define WS_JSPART (WS_YROT + 512)                  // 236*2272 floats

typedef __attribute__((ext_vector_type(8))) short short8;
typedef __attribute__((ext_vector_type(4))) float f32x4;

// fp32 -> bf16 round-to-nearest-even
__device__ __forceinline__ unsigned short f2bf(float x) {
  unsigned int u = __float_as_uint(x);
  u = (u + 0x7fffu + ((u >> 16) & 1u)) >> 16;
  return (unsigned short)u;
}

// ---------------- rodrigues (matches jax reference in fp32) ----------------
__device__ __forceinline__ void rodrigues9(float rx, float ry, float rz, float* R) {
  float a0 = rx + 1e-8f, a1 = ry + 1e-8f, a2 = rz + 1e-8f;
  float angle = sqrtf(a0 * a0 + a1 * a1 + a2 * a2);
  float inv = 1.0f / angle;
  float x = rx * inv, y = ry * inv, z = rz * inv;
  float s = sinf(angle), c = cosf(angle);
  float t = 1.0f - c;
  float xy = x * y, xz = x * z, yz = y * z;
  R[0] = 1.0f - t * (y * y + z * z);
  R[1] = -s * z + t * xy;
  R[2] =  s * y + t * xz;
  R[3] =  s * z + t * xy;
  R[4] = 1.0f - t * (x * x + z * z);
  R[5] = -s * x + t * yz;
  R[6] = -s * y + t * xz;
  R[7] =  s * x + t * yz;
  R[8] = 1.0f - t * (x * x + y * y);
}

// ---------------- k_aux UNIFIED: 236 blocks; each stages 64 BTn rows of sd ONCE
// and produces BOTH the bf16 BTn rows AND the JS partials for those rows. ----
__global__ __launch_bounds__(512) void k_aux(
    const float* __restrict__ sd, const float* __restrict__ pd,
    const float* __restrict__ jreg, const float* __restrict__ vt,
    unsigned int* __restrict__ btn_u, float* __restrict__ JSpart) {
  __shared__ __align__(16) unsigned char sm[44544];
  float* sdt = (float*)sm;                          // 64 x 152 f32 @0      (38,912 B)
  unsigned short* pdt = (unsigned short*)(sm + 38912); // 64 x 38 bf16      ( 4,864 B)
  float* vtc = (float*)(sm + 43776);                // 64 f32               (   256 B)
  float* jt  = (float*)(sm + 44032);                // 5 x 22 f32           (   440 B)
  const int t = threadIdx.x;
  const int bid = blockIdx.x;                       // 0..235
  const int n0 = bid * 64;
  const int v0 = n0 / 3;

  // sd rows (linear, coalesced; rows >= cV3 zeroed)
  for (int idx = t; idx < 9600; idx += 512) {
    size_t g = (size_t)n0 * 150 + idx;
    float v = (g < (size_t)cV3 * 150) ? sd[g] : 0.f;
    int row = idx / 150, col = idx - row * 150;
    sdt[row * 152 + col] = v;
  }
  // pd columns (coalesced over n)
  for (int e = t; e < 2304; e += 512) {
    int kk = e >> 6, ln = e & 63;
    int n = n0 + ln;
    pdt[ln * 38 + kk] = f2bf((n < cV3) ? pd[(size_t)kk * cV3 + n] : 0.f);
  }
  // v_template values for these rows (JS l=150 term)
  if (t < 64) {
    int n = n0 + t;
    vtc[t] = (n < cV3) ? vt[n] : 0.f;
  }
  // jreg slice: 5 joints x 22 vertices covered by this block
  if (t >= 64 && t < 174) {
    int e = t - 64;
    int j = e / 22, vi = e - j * 22;
    int v = v0 + vi;
    jt[j * 22 + vi] = (v < cV) ? jreg[j * cV + v] : 0.f;
  }
  __syncthreads();

  // JS partials: thread (c,l); sum over the ~22 vertices whose row 3v+c is here
  if (t < 453) {
    int c = t / 151, l = t - c * 151;
    const int base = 3 * v0 + c - n0;               // row of vertex v0, component c
    float acc[5] = {0.f, 0.f, 0.f, 0.f, 0.f};
#pragma unroll
    for (int vi = 0; vi < 22; ++vi) {
      int r = base + 3 * vi;
      if (r >= 0 && r < 64) {
        float x = (l < 150) ? sdt[r * 152 + l] : vtc[r];
#pragma unroll
        for (int j = 0; j < 5; ++j)
          acc[j] = fmaf(jt[j * 22 + vi], x, acc[j]);
      }
    }
#pragma unroll
    for (int j = 0; j < 5; ++j)
      JSpart[(size_t)bid * 2272 + (j * 3 + c) * 151 + l] = acc[j];
  }

  // emit BTn rows (96 dwords each), coalesced
  for (int e = t; e < 6144; e += 512) {
    int row = e / 96, d = e - row * 96;
    int n = n0 + row;
    if (n < cNPAD) {
      unsigned int wv;
      if (d < 75) {
        wv = (unsigned int)f2bf(sdt[row * 152 + 2 * d]) |
             ((unsigned int)f2bf(sdt[row * 152 + 2 * d + 1]) << 16);
      } else if (d < 93) {
        int p = (d - 75) * 2;
        wv = (unsigned int)pdt[row * 38 + p] |
             ((unsigned int)pdt[row * 38 + p + 1] << 16);
      } else {
        wv = 0u;
      }
      btn_u[(size_t)n * 96 + d] = wv;
    }
  }
}

// ---------------- k_jsred: 236 partials -> JS2[l][16]; 8 threads per element ----------------
__global__ __launch_bounds__(256) void k_jsred(const float* __restrict__ JSpart,
                                               float* __restrict__ JS2) {
  __shared__ float red[256];
  const int t = threadIdx.x;
  const int e = blockIdx.x * 32 + (t & 31);
  const int pg = t >> 5;
  float s = 0.f;
  if (e < 2265) {
#pragma unroll 8
    for (int p = pg; p < 236; p += 8)
      s += JSpart[(size_t)p * 2272 + e];
  }
  red[t] = s;
  __syncthreads();
  if (t < 128) red[t] += red[t + 128];
  __syncthreads();
  if (t < 64) red[t] += red[t + 64];
  __syncthreads();
  if (t < 32) {
    float v = red[t] + red[t + 32];
    if (e < 2265) {
      int jc = e / 151, l = e - jc * 151;
      JS2[l * 16 + jc] = v;
    }
  }
}

// ---------------- k_batch: joints, rot mats, chain, A_rel, y_rot + ATm bf16 rows ----------
__global__ __launch_bounds__(256) void k_batch(
    const float* __restrict__ shp, const float* __restrict__ expr,
    const float* __restrict__ pose, const float* __restrict__ eyep,
    const float* __restrict__ JS2g, float* __restrict__ Arel,
    int* __restrict__ yrot, unsigned int* __restrict__ atm_u) {
  __shared__ float js2[151 * 16];
  __shared__ float sb[32 * 153];
  __shared__ float pfs[32 * 36];
  const int t = threadIdx.x;
  const int b0 = blockIdx.x * 32;
  for (int i = t; i < 151 * 16; i += 256) js2[i] = JS2g[i];
  for (int e = t; e < 3200; e += 256) {
    int bl = e / 100, l = e - bl * 100;
    sb[bl * 153 + l] = shp[(size_t)(b0 + bl) * 100 + l];
  }
  for (int e = t; e < 1600; e += 256) {
    int bl = e / 50, l = e - bl * 50;
    sb[bl * 153 + 100 + l] = expr[(size_t)(b0 + bl) * 50 + l];
  }
  __syncthreads();

  if (t < 32) {
    int b = b0 + t;
    float jnt[5][3];
    {
      const f32x4* J4 = (const f32x4*)(js2 + 150 * 16);
      f32x4 A = J4[0], Bq = J4[1], Cq = J4[2], Dq = J4[3];
      jnt[0][0] = A.x;  jnt[0][1] = A.y;  jnt[0][2] = A.z;
      jnt[1][0] = A.w;  jnt[1][1] = Bq.x; jnt[1][2] = Bq.y;
      jnt[2][0] = Bq.z; jnt[2][1] = Bq.w; jnt[2][2] = Cq.x;
      jnt[3][0] = Cq.y; jnt[3][1] = Cq.z; jnt[3][2] = Cq.w;
      jnt[4][0] = Dq.x; jnt[4][1] = Dq.y; jnt[4][2] = Dq.z;
    }
    for (int l = 0; l < 150; ++l) {
      const f32x4* J4 = (const f32x4*)(js2 + l * 16);
      f32x4 A = J4[0], Bq = J4[1], Cq = J4[2], Dq = J4[3];
      float beta = sb[t * 153 + l];
      jnt[0][0] = fmaf(beta, A.x,  jnt[0][0]);
      jnt[0][1] = fmaf(beta, A.y,  jnt[0][1]);
      jnt[0][2] = fmaf(beta, A.z,  jnt[0][2]);
      jnt[1][0] = fmaf(beta, A.w,  jnt[1][0]);
      jnt[1][1] = fmaf(beta, Bq.x, jnt[1][1]);
      jnt[1][2] = fmaf(beta, Bq.y, jnt[1][2]);
      jnt[2][0] = fmaf(beta, Bq.z, jnt[2][0]);
      jnt[2][1] = fmaf(beta, Bq.w, jnt[2][1]);
      jnt[2][2] = fmaf(beta, Cq.x, jnt[2][2]);
      jnt[3][0] = fmaf(beta, Cq.y, jnt[3][0]);
      jnt[3][1] = fmaf(beta, Cq.z, jnt[3][1]);
      jnt[3][2] = fmaf(beta, Cq.w, jnt[3][2]);
      jnt[4][0] = fmaf(beta, Dq.x, jnt[4][0]);
      jnt[4][1] = fmaf(beta, Dq.y, jnt[4][1]);
      jnt[4][2] = fmaf(beta, Dq.z, jnt[4][2]);
    }
    float fp[5][3];
    fp[0][0] = pose[b * 6 + 0]; fp[0][1] = pose[b * 6 + 1]; fp[0][2] = pose[b * 6 + 2];
    fp[1][0] = 0.f; fp[1][1] = 0.f; fp[1][2] = 0.f;
    fp[2][0] = pose[b * 6 + 3]; fp[2][1] = pose[b * 6 + 4]; fp[2][2] = pose[b * 6 + 5];
    fp[3][0] = eyep[b * 6 + 0]; fp[3][1] = eyep[b * 6 + 1]; fp[3][2] = eyep[b * 6 + 2];
    fp[4][0] = eyep[b * 6 + 3]; fp[4][1] = eyep[b * 6 + 4]; fp[4][2] = eyep[b * 6 + 5];
    float R[5][9];
#pragma unroll
    for (int j = 0; j < 5; ++j) rodrigues9(fp[j][0], fp[j][1], fp[j][2], R[j]);
#pragma unroll
    for (int j = 1; j < 5; ++j)
#pragma unroll
      for (int r = 0; r < 9; ++r) {
        float id = (r == 0 || r == 4 || r == 8) ? 1.f : 0.f;
        pfs[t * 36 + (j - 1) * 9 + r] = R[j][r] - id;
      }
    float rel[5][3];
#pragma unroll
    for (int c = 0; c < 3; ++c) {
      rel[0][c] = jnt[0][c];
      rel[1][c] = jnt[1][c] - jnt[0][c];
      rel[2][c] = jnt[2][c] - jnt[1][c];
      rel[3][c] = jnt[3][c] - jnt[1][c];
      rel[4][c] = jnt[4][c] - jnt[1][c];
    }
    float GR[5][9], Gt[5][3];
#pragma unroll
    for (int r = 0; r < 9; ++r) GR[0][r] = R[0][r];
#pragma unroll
    for (int c = 0; c < 3; ++c) Gt[0][c] = rel[0][c];
    const int par[5] = {0, 0, 1, 1, 1};
#pragma unroll
    for (int j = 1; j < 5; ++j) {
      int p = par[j];
#pragma unroll
      for (int r = 0; r < 3; ++r) {
#pragma unroll
        for (int cc = 0; cc < 3; ++cc)
          GR[j][r * 3 + cc] = GR[p][r * 3 + 0] * R[j][0 + cc] +
                              GR[p][r * 3 + 1] * R[j][3 + cc] +
                              GR[p][r * 3 + 2] * R[j][6 + cc];
        Gt[j][r] = Gt[p][r] + GR[p][r * 3 + 0] * rel[j][0] +
                              GR[p][r * 3 + 1] * rel[j][1] +
                              GR[p][r * 3 + 2] * rel[j][2];
      }
    }
#pragma unroll
    for (int j = 0; j < 5; ++j)
#pragma unroll
      for (int r = 0; r < 3; ++r) {
        float tj = Gt[j][r] - (GR[j][r * 3 + 0] * jnt[j][0] +
                               GR[j][r * 3 + 1] * jnt[j][1] +
                               GR[j][r * 3 + 2] * jnt[j][2]);
        Arel[b * 60 + j * 12 + r * 4 + 0] = GR[j][r * 3 + 0];
        Arel[b * 60 + j * 12 + r * 4 + 1] = GR[j][r * 3 + 1];
        Arel[b * 60 + j * 12 + r * 4 + 2] = GR[j][r * 3 + 2];
        Arel[b * 60 + j * 12 + r * 4 + 3] = tj;
      }
    float Ra[9], Rb[9];
    rodrigues9(fp[1][0], fp[1][1], fp[1][2], Ra);
    rodrigues9(fp[0][0], fp[0][1], fp[0][2], Rb);
    float r00 = Rb[0] * Ra[0] + Rb[1] * Ra[3] + Rb[2] * Ra[6];
    float r10 = Rb[3] * Ra[0] + Rb[4] * Ra[3] + Rb[5] * Ra[6];
    float r20 = Rb[6] * Ra[0] + Rb[7] * Ra[3] + Rb[8] * Ra[6];
    float sy = sqrtf(r00 * r00 + r10 * r10);
    float ydeg = atan2f(-r20, sy) * 57.29577951308232f;
    int y = (int)rintf(fminf(ydeg, 39.0f));
    if (y < 0) y = (y < -39) ? 78 : (39 - y);
    yrot[b] = y;
  }
  __syncthreads();

#pragma unroll
  for (int it = 0; it < 12; ++it) {
    int e = t + it * 256;
    int bl = e / 96, d = e - bl * 96;
    unsigned int wv;
    if (d < 75) {
      wv = (unsigned int)f2bf(sb[bl * 153 + 2 * d]) |
           ((unsigned int)f2bf(sb[bl * 153 + 2 * d + 1]) << 16);
    } else if (d < 93) {
      wv = (unsigned int)f2bf(pfs[bl * 36 + (d - 75) * 2]) |
           ((unsigned int)f2bf(pfs[bl * 36 + (d - 75) * 2 + 1]) << 16);
    } else {
      wv = 0u;
    }
    atm_u[(size_t)(b0 + bl) * 96 + d] = wv;
  }
}

// ---------------- k_main v7: r6's single-wave structure (2512 x 64thr, zero
// barriers, 12 waves/CU) + r4's lane-contiguous staged stores. r6 lesson: the
// lane=batch direct stores were 64-lines/instr scattered (WRITE 116 MB churn,
// FETCH 24 MB RMW). Fix: compute 48 outputs into REGISTERS, overlay Os[64x49]
// on Pf's LDS (single-wave aliasing ordered by compiler), then 48 wave-stores
// with lanes contiguous inside 48-float batch rows (~7 lines/instr, ~9x fewer).
// Tripwires: WRITE > 45 MB = boundary churn (not granule); dur ~40 w/ clean
// traffic = unmodeled structural floor, re-profile.
__global__ __launch_bounds__(64) void k_main(
    const unsigned short* __restrict__ BTn, const unsigned short* __restrict__ ATm,
    const float* __restrict__ Arel, const float* __restrict__ vtempl,
    const float* __restrict__ lbw, float* __restrict__ out) {
  __shared__ float Pf[3328];             // 13,312 B: GEMM transpose (48*66) then Os (64*49)

  const int bid = blockIdx.x;            // 2512 = 314 nb * 8 mb (nb-adjacent same-XCD)
  const int nb = bid >> 3, mb = bid & 7;
  const int L = threadIdx.x;             // 0..63
  const int lr = L & 15, lq = L >> 4;

  const unsigned short* abase = ATm + ((size_t)mb * 64 + lr) * 192 + lq * 8;
  const unsigned short* bbase = BTn + ((size_t)nb * 48 + lr) * 192 + lq * 8;

  f32x4 acc[4][3];
#pragma unroll
  for (int mt = 0; mt < 4; ++mt)
#pragma unroll
    for (int nt = 0; nt < 3; ++nt) acc[mt][nt] = (f32x4){0.f, 0.f, 0.f, 0.f};

  // depth-2 ring: 4 A-frags (m-tiles) + 3 B-frags (n-tiles) per k-step
  short8 Ar[2][4], Br[2][3];
#pragma unroll
  for (int mt = 0; mt < 4; ++mt) Ar[0][mt] = *(const short8*)(abase + mt * 16 * 192);
#pragma unroll
  for (int nt = 0; nt < 3; ++nt) Br[0][nt] = *(const short8*)(bbase + nt * 16 * 192);

#pragma unroll
  for (int ks = 0; ks < 6; ++ks) {
    const int cur = ks & 1, nxt = cur ^ 1;   // static after unroll
    if (ks < 5) {
      const int ko = (ks + 1) * 32;
#pragma unroll
      for (int mt = 0; mt < 4; ++mt)
        Ar[nxt][mt] = *(const short8*)(abase + mt * 16 * 192 + ko);
#pragma unroll
      for (int nt = 0; nt < 3; ++nt)
        Br[nxt][nt] = *(const short8*)(bbase + nt * 16 * 192 + ko);
    }
#pragma unroll
    for (int nt = 0; nt < 3; ++nt)
#pragma unroll
      for (int mt = 0; mt < 4; ++mt)
        acc[mt][nt] = __builtin_amdgcn_mfma_f32_16x16x32_bf16(
            Ar[cur][mt], Br[cur][nt], acc[mt][nt], 0, 0, 0);
  }

  // acc -> Pf[n_loc][m]  (C layout: col(lane&15)->n, row((lane>>4)*4+reg)->m)
#pragma unroll
  for (int mt = 0; mt < 4; ++mt)
#pragma unroll
    for (int nt = 0; nt < 3; ++nt) {
      int n_loc = nt * 16 + lr;
      int m = mt * 16 + lq * 4;
      *(f32x4*)(Pf + n_loc * 66 + m) = acc[mt][nt];
    }

  // lane L owns batch b = mb*64 + L
  const int b = mb * 64 + L;
  const float* qb = Arel + (size_t)b * 60;
  f32x4 ar[15];
#pragma unroll
  for (int r = 0; r < 15; ++r) ar[r] = *(const f32x4*)(qb + 4 * r);

  // ---- compute 48 outputs into registers (single wave: LDS ordering via waitcnt) ----
  const int vg0 = nb * 16;
  float o48[48];
#pragma unroll
  for (int vl = 0; vl < 16; ++vl) {
    const int v = vg0 + vl;
    const bool ok = (v < cV);            // uniform across lanes
    float vt0 = ok ? vtempl[v * 3 + 0] : 0.f;
    float vt1 = ok ? vtempl[v * 3 + 1] : 0.f;
    float vt2 = ok ? vtempl[v * 3 + 2] : 0.f;
    float px = Pf[(vl * 3 + 0) * 66 + L] + vt0;
    float py = Pf[(vl * 3 + 1) * 66 + L] + vt1;
    float pz = Pf[(vl * 3 + 2) * 66 + L] + vt2;
    float o0 = 0.f, o1 = 0.f, o2 = 0.f;
#pragma unroll
    for (int j = 0; j < 5; ++j) {
      f32x4 q0 = ar[3 * j + 0], q1 = ar[3 * j + 1], q2 = ar[3 * j + 2];
      float s0 = q0.x * px + q0.y * py + q0.z * pz + q0.w;
      float s1 = q1.x * px + q1.y * py + q1.z * pz + q1.w;
      float s2 = q2.x * px + q2.y * py + q2.z * pz + q2.w;
      float wj = ok ? lbw[v * 5 + j] : 0.f;   // uniform -> scalar broadcast
      o0 = fmaf(wj, s0, o0);
      o1 = fmaf(wj, s1, o1);
      o2 = fmaf(wj, s2, o2);
    }
    o48[vl * 3 + 0] = o0;
    o48[vl * 3 + 1] = o1;
    o48[vl * 3 + 2] = o2;
  }

  // ---- overlay Os on Pf (all Pf reads above complete in program order) ----
  // Os[b_loc*49 + k]: stride 49 -> <=2-way bank aliasing on lane-major writes (free)
  float* Os = Pf;
#pragma unroll
  for (int k = 0; k < 48; ++k) Os[L * 49 + k] = o48[k];

  // ---- store: lanes contiguous within 48-float batch rows (~7 lines/instr) ----
  const size_t cv3 = (size_t)cV * 3;
  float* ob = out + (size_t)(mb * 64) * cv3 + (size_t)vg0 * 3;
  const int fmax = (nb < 313) ? 48 : 45;    // nb==313: verts 5008..5022 -> 45 floats
#pragma unroll
  for (int s = 0; s < 48; ++s) {
    int idx = s * 64 + L;
    int bb = idx / 48, f = idx - bb * 48;
    if (f < fmax)
      ob[(size_t)bb * cv3 + f] = Os[bb * 49 + f];
  }
}

// ---------------- k_lmk: barycentric landmark gather, component-parallel ----
__global__ __launch_bounds__(512) void k_lmk(
    const float* __restrict__ verts, const int* __restrict__ faces,
    const int* __restrict__ lmkf, const float* __restrict__ lmkb,
    const int* __restrict__ dynf, const float* __restrict__ dynb,
    const int* __restrict__ fullf, const float* __restrict__ fullb,
    const int* __restrict__ yrot, float* __restrict__ out) {
  int id = blockIdx.x * 512 + threadIdx.x;
  if (id >= cB * cLF * 6) return;
  int c = id % 3;
  int q = id / 3;
  int sel = q & 1;
  int r = q >> 1;
  int b = r / cLF, l = r - b * cLF;
  const float* vb = verts + (size_t)b * cV * 3;
  int f; float w0, w1, w2; size_t o;
  if (sel == 0) {
    if (l < cLD) {
      int yb = yrot[b];
      f = dynf[yb * cLD + l];
      const float* bp = dynb + ((size_t)yb * cLD + l) * 3;
      w0 = bp[0]; w1 = bp[1]; w2 = bp[2];
    } else {
      f = lmkf[l - cLD];
      const float* bp = lmkb + (size_t)(l - cLD) * 3;
      w0 = bp[0]; w1 = bp[1]; w2 = bp[2];
    }
    o = OUT_V + ((size_t)b * cLF + l) * 3;
  } else {
    f = fullf[l];
    const float* bp = fullb + (size_t)l * 3;
    w0 = bp[0]; w1 = bp[1]; w2 = bp[2];
    o = OUT_V + OUT_L + ((size_t)b * cLF + l) * 3;
  }
  int i0 = faces[f * 3 + 0] * 3, i1 = faces[f * 3 + 1] * 3, i2 = faces[f * 3 + 2] * 3;
  out[o + c] = w0 * vb[i0 + c] + w1 * vb[i1 + c] + w2 * vb[i2 + c];
}

// ---------------- launch ----------------
extern "C" void kernel_launch(void* const* d_in, const int* in_sizes, int n_in,
                              void* d_out, int out_size, void* d_ws, size_t ws_size,
                              hipStream_t stream) {
  (void)in_sizes; (void)n_in; (void)out_size; (void)ws_size;
  const float* shp  = (const float*)d_in[0];
  const float* expr = (const float*)d_in[1];
  const float* pose = (const float*)d_in[2];
  const float* eyep = (const float*)d_in[3];
  const float* vt   = (const float*)d_in[4];
  const float* sd   = (const float*)d_in[5];
  const float* pd   = (const float*)d_in[6];
  const float* jreg = (const float*)d_in[7];
  const float* lbw  = (const float*)d_in[8];
  const int*   fcs  = (const int*)d_in[9];
  const int*   lmkf = (const int*)d_in[10];
  const float* lmkb = (const float*)d_in[11];
  const int*   dynf = (const int*)d_in[12];
  const float* dynb = (const float*)d_in[13];
  const int*   fullf= (const int*)d_in[14];
  const float* fullb= (const float*)d_in[15];
  float* out = (float*)d_out;
  float* ws  = (float*)d_ws;

  unsigned int*   btn  = (unsigned int*)(ws + WS_BTN);
  unsigned short* ATm  = (unsigned short*)(ws + WS_ATM);
  float* JS2    = ws + WS_JS2;
  float* Arel   = ws + WS_AREL;
  int*   yrot   = (int*)(ws + WS_YROT);
  float* JSpart = ws + WS_JSPART;

  k_aux<<<236, 512, 0, stream>>>(sd, pd, jreg, vt, btn, JSpart);
  k_jsred<<<71, 256, 0, stream>>>(JSpart, JS2);
  k_batch<<<16, 256, 0, stream>>>(shp, expr, pose, eyep, JS2, Arel, yrot,
                                  (unsigned int*)ATm);
  k_main<<<2512, 64, 0, stream>>>((unsigned short*)btn, ATm, Arel, vt, lbw, out);
  k_lmk<<<408, 512, 0, stream>>>(out, fcs, lmkf, lmkb, dynf, dynb, fullf, fullb, yrot, out);
}